// Round 1
// baseline (1998.133 us; speedup 1.0000x reference)
//
#include <hip/hip_runtime.h>

typedef _Float16 f16;
typedef f16 f16x8 __attribute__((ext_vector_type(8)));
typedef f16 f16x4 __attribute__((ext_vector_type(4)));
typedef float f32x4 __attribute__((ext_vector_type(4)));

#define B_ 64
#define C_ 512
#define X2D_ELEMS ((size_t)134217728)  // 64*512*64*64

// ---------------------------------------------------------------------------
// conv-as-GEMM: Y[co][n] = relu( sum_k W[co][k] * X[k][n] + bias[co] )
//   MODE 0: first layer, k=1 conv, input fp32 in [B][C][L] layout, K=512
//   MODE 1: k=2 conv, input f16 in [C][B*Lin] compact layout, K=1024,
//           X[2*ci+t][n] = xin[ci*Nin + b*Lin + l + t],  n = b*Lout + l
// Epilogue also scatters fp32 result onto the strided diagonal of x2d.
// ---------------------------------------------------------------------------
template<int MODE>
__global__ __launch_bounds__(256)
void conv_gemm(const void* __restrict__ xin_, const float* __restrict__ w,
               const float* __restrict__ bias, f16* __restrict__ yout,
               float* __restrict__ x2d, int Lin, int Lout, int K,
               int stride, int offset)
{
    const int N = B_ * Lout;
    __shared__ __align__(16) f16 As[64 * 64];
    __shared__ __align__(16) f16 Bs[64 * 64];
    const int tid  = threadIdx.x;
    const int lane = tid & 63;
    const int wv   = tid >> 6;
    const int wm   = wv >> 1, wn = wv & 1;
    const int n0 = blockIdx.x * 64, m0 = blockIdx.y * 64;

    // B-staging coordinates (fixed n per thread)
    const int bn = tid & 63;
    int n_g = n0 + bn; if (n_g > N - 1) n_g = N - 1;   // clamp tail (cols >= N discarded)
    const unsigned bb = (unsigned)n_g / (unsigned)Lout;
    const int bl = n_g - (int)bb * Lout;
    const int Nin = B_ * Lin;
    const int binbase = (int)bb * Lin + bl;            // MODE1 input n-index
    const int swzB = (bn & 7) << 3;

    f32x4 acc[2][2] = {};

    for (int kt = 0; kt < K; kt += 64) {
        // ---- stage A tile: w[m0+m][kt+k] fp32 -> f16, swizzled LDS [m][k]
        {
            const int m  = tid >> 2;
            const int k4 = (tid & 3) << 4;
            const float* src = w + (size_t)(m0 + m) * K + kt + k4;
            const int swzA = (m & 7) << 3;
            #pragma unroll
            for (int i = 0; i < 4; i++) {
                const float4 v = *(const float4*)(src + 4 * i);
                f16x4 h; h[0] = (f16)v.x; h[1] = (f16)v.y; h[2] = (f16)v.z; h[3] = (f16)v.w;
                *(f16x4*)&As[m * 64 + ((k4 + 4 * i) ^ swzA)] = h;
            }
        }
        // ---- stage B tile: X[kt..kt+63][n0..n0+63], swizzled LDS [n][k]
        if (MODE == 0) {
            const float* xf = (const float*)xin_;
            #pragma unroll
            for (int it = 0; it < 16; it++) {
                const int kk = (tid >> 6) + (it << 2);        // 0..63 (k = ci)
                const float v = xf[(size_t)bb * (C_ * B_) + (size_t)(kt + kk) * B_ + bl];
                Bs[bn * 64 + (kk ^ swzB)] = (f16)v;
            }
        } else {
            const f16* xh = (const f16*)xin_;
            #pragma unroll
            for (int it = 0; it < 8; it++) {
                const int cis = (tid >> 6) + (it << 2);       // 0..31
                const int ci  = (kt >> 1) + cis;
                const f16* p = xh + (size_t)ci * Nin + binbase;
                union { f16 h[2]; unsigned u; } pk;
                pk.h[0] = p[0]; pk.h[1] = p[1];               // taps t=0,1
                *(unsigned*)&Bs[bn * 64 + ((cis << 1) ^ swzB)] = pk.u;
            }
        }
        __syncthreads();
        // ---- MFMA: 2 k-steps of 32
        #pragma unroll
        for (int ks = 0; ks < 64; ks += 32) {
            f16x8 af[2], bf[2];
            #pragma unroll
            for (int mf = 0; mf < 2; mf++) {
                const int m  = wm * 32 + mf * 16 + (lane & 15);
                const int kk = ks + ((lane >> 4) << 3);
                af[mf] = *(const f16x8*)&As[m * 64 + (kk ^ ((m & 7) << 3))];
            }
            #pragma unroll
            for (int nf = 0; nf < 2; nf++) {
                const int nn = wn * 32 + nf * 16 + (lane & 15);
                const int kk = ks + ((lane >> 4) << 3);
                bf[nf] = *(const f16x8*)&Bs[nn * 64 + (kk ^ ((nn & 7) << 3))];
            }
            #pragma unroll
            for (int mf = 0; mf < 2; mf++)
                #pragma unroll
                for (int nf = 0; nf < 2; nf++)
                    acc[mf][nf] = __builtin_amdgcn_mfma_f32_16x16x32_f16(
                        af[mf], bf[nf], acc[mf][nf], 0, 0, 0);
        }
        __syncthreads();
    }

    // ---- epilogue: bias + relu, write f16 chain buffer + fp32 diagonal scatter
    #pragma unroll
    for (int nf = 0; nf < 2; nf++) {
        const int nc = n0 + wn * 32 + nf * 16 + (lane & 15);
        if (nc < N) {
            const unsigned b2i = (unsigned)nc / (unsigned)Lout;
            const int l = nc - (int)b2i * Lout;
            float* x2p = x2d + (size_t)b2i * (C_ * 4096) + (size_t)l * stride * 65 + offset;
            #pragma unroll
            for (int mf = 0; mf < 2; mf++) {
                #pragma unroll
                for (int j = 0; j < 4; j++) {
                    const int row = wm * 32 + mf * 16 + ((lane >> 4) << 2) + j;
                    const int co  = m0 + row;
                    float v = acc[mf][nf][j] + bias[co];
                    v = fmaxf(v, 0.0f);
                    yout[(size_t)co * N + nc] = (f16)v;
                    x2p[(size_t)co * 4096] = v;
                }
            }
        }
    }
}

// MaxPool1d(k=3, s=2) + relu + f16 chain write + fp32 diagonal scatter
__global__ void maxpool_scatter(const f16* __restrict__ xin, f16* __restrict__ yout,
                                float* __restrict__ x2d, int Lin, int Lp,
                                int stride, int offset)
{
    const int Nout = B_ * Lp;
    const int n = blockIdx.x * 256 + threadIdx.x;
    const int c = blockIdx.y;
    if (n >= Nout) return;
    const unsigned b = (unsigned)n / (unsigned)Lp;
    const int l = n - (int)b * Lp;
    const f16* s = xin + (size_t)c * (B_ * Lin) + (size_t)b * Lin + 2 * l;
    float v = fmaxf(fmaxf((float)s[0], (float)s[1]), (float)s[2]);
    v = fmaxf(v, 0.0f);
    yout[(size_t)c * Nout + n] = (f16)v;
    x2d[((size_t)b * C_ + c) * 4096 + (size_t)l * stride * 65 + offset] = v;
}

// mask[i][j]: closed-form union of all 32 written diagonals
__global__ void mask_kernel(float* __restrict__ mout)
{
    const int t = blockIdx.x * 256 + threadIdx.x;   // 0..4095
    const int i = t >> 6, j = t & 63;
    const int d = j - i;
    const bool m = (d >= 0 && d <= 15) ||
                   (d >= 17 && d <= 31 && (d & 1) && ((i & 1) == 0)) ||
                   (d >= 35 && d <= 63 && (((d - 35) & 3) == 0) && ((i & 3) == 0));
    mout[t] = m ? 1.0f : 0.0f;
}

extern "C" void kernel_launch(void* const* d_in, const int* in_sizes, int n_in,
                              void* d_out, int out_size, void* d_ws, size_t ws_size,
                              hipStream_t stream)
{
    const float* x  = (const float*)d_in[0];
    const float* w1 = (const float*)d_in[1];
    const float* b1 = (const float*)d_in[2];
    const float* w2 = (const float*)d_in[3];
    const float* b2 = (const float*)d_in[4];
    float* x2d   = (float*)d_out;
    float* maskp = x2d + X2D_ELEMS;
    f16* buf0 = (f16*)d_ws;
    f16* buf1 = buf0 + (size_t)C_ * 4096;   // 4 MB each, 8 MB total

    hipMemsetAsync(d_out, 0, X2D_ELEMS * sizeof(float), stream);
    mask_kernel<<<16, 256, 0, stream>>>(maskp);

    const int counts[3] = {16, 8, 8};
    int stride = 1, offset = 0, L = 64, k2 = 0;
    f16* cur = buf0; f16* nxt = buf1;
    for (int level = 0; level < 3; level++) {
        for (int order = 0; order < counts[level]; order++) {
            if (level == 0 && order == 0) {
                dim3 g(64, 8);
                conv_gemm<0><<<g, 256, 0, stream>>>(x, w1, b1, buf0, x2d,
                                                    64, 64, 512, stride, offset);
                cur = buf0; nxt = buf1;
            } else if (level > 0 && order == 0) {
                const int Lp = (L - 3) / 2 + 1;
                dim3 g((B_ * Lp + 255) / 256, C_);
                maxpool_scatter<<<g, 256, 0, stream>>>(cur, nxt, x2d, L, Lp, stride, offset);
                L = Lp; f16* t = cur; cur = nxt; nxt = t;
            } else {
                const int Lout = L - 1;
                const int N = B_ * Lout;
                dim3 g((N + 63) / 64, 8);
                conv_gemm<1><<<g, 256, 0, stream>>>(cur, w2 + (size_t)k2 * C_ * C_ * 2,
                                                    b2 + (size_t)k2 * C_, nxt, x2d,
                                                    L, Lout, 1024, stride, offset);
                k2++; L = Lout; f16* t = cur; cur = nxt; nxt = t;
            }
            offset += stride;
        }
        offset += stride; stride *= 2;
    }
}

// Round 2
// 1806.208 us; speedup vs baseline: 1.1063x; 1.1063x over previous
//
#include <hip/hip_runtime.h>

typedef _Float16 f16;
typedef f16 f16x8 __attribute__((ext_vector_type(8)));
typedef f16 f16x4 __attribute__((ext_vector_type(4)));
typedef float f32x4 __attribute__((ext_vector_type(4)));

#define B_ 64
#define C_ 512
#define X2D_ELEMS ((size_t)134217728)  // 64*512*64*64
#define COLS_TOTAL 1104               // sum of L_t over all 32 layers
#define COLSLOT 32768                 // C_*B_ elems per column

// ---------------------------------------------------------------------------
// conv-as-GEMM: Y[co][n] = relu( sum_k W[co][k] * X[k][n] + bias[co] )
//   MODE 0: first layer, k=1 conv, input fp32 [B][C][L], K=512
//   MODE 1: k=2 conv, input f16 [C][B*Lin] compact, K=1024
//   SC 1:   legacy fallback — also scatter fp32 onto x2d diagonal
// ---------------------------------------------------------------------------
template<int MODE, int SC>
__global__ __launch_bounds__(256)
void conv_gemm(const void* __restrict__ xin_, const float* __restrict__ w,
               const float* __restrict__ bias, f16* __restrict__ yout,
               float* __restrict__ x2d, int Lin, int Lout, int K,
               int stride, int offset)
{
    const int N = B_ * Lout;
    __shared__ __align__(16) f16 As[64 * 64];
    __shared__ __align__(16) f16 Bs[64 * 64];
    const int tid  = threadIdx.x;
    const int lane = tid & 63;
    const int wv   = tid >> 6;
    const int wm   = wv >> 1, wn = wv & 1;
    const int n0 = blockIdx.x * 64, m0 = blockIdx.y * 64;

    const int bn = tid & 63;
    int n_g = n0 + bn; if (n_g > N - 1) n_g = N - 1;   // clamp tail
    const unsigned bb = (unsigned)n_g / (unsigned)Lout;
    const int bl = n_g - (int)bb * Lout;
    const int Nin = B_ * Lin;
    const int binbase = (int)bb * Lin + bl;
    const int swzB = (bn & 7) << 3;

    f32x4 acc[2][2] = {};

    for (int kt = 0; kt < K; kt += 64) {
        {   // stage A: w[m0+m][kt+k] fp32 -> f16, swizzled LDS [m][k]
            const int m  = tid >> 2;
            const int k4 = (tid & 3) << 4;
            const float* src = w + (size_t)(m0 + m) * K + kt + k4;
            const int swzA = (m & 7) << 3;
            #pragma unroll
            for (int i = 0; i < 4; i++) {
                const float4 v = *(const float4*)(src + 4 * i);
                f16x4 h; h[0] = (f16)v.x; h[1] = (f16)v.y; h[2] = (f16)v.z; h[3] = (f16)v.w;
                *(f16x4*)&As[m * 64 + ((k4 + 4 * i) ^ swzA)] = h;
            }
        }
        if (MODE == 0) {   // stage B from fp32 [B][C][L]
            const float* xf = (const float*)xin_;
            #pragma unroll
            for (int it = 0; it < 16; it++) {
                const int kk = (tid >> 6) + (it << 2);
                const float v = xf[(size_t)bb * (C_ * 64) + (size_t)(kt + kk) * 64 + bl];
                Bs[bn * 64 + (kk ^ swzB)] = (f16)v;
            }
        } else {           // stage B from f16 [C][B*Lin], taps t=0,1
            const f16* xh = (const f16*)xin_;
            #pragma unroll
            for (int it = 0; it < 8; it++) {
                const int cis = (tid >> 6) + (it << 2);
                const int ci  = (kt >> 1) + cis;
                const f16* p = xh + (size_t)ci * Nin + binbase;
                union { f16 h[2]; unsigned u; } pk;
                pk.h[0] = p[0]; pk.h[1] = p[1];
                *(unsigned*)&Bs[bn * 64 + ((cis << 1) ^ swzB)] = pk.u;
            }
        }
        __syncthreads();
        #pragma unroll
        for (int ks = 0; ks < 64; ks += 32) {
            f16x8 af[2], bf[2];
            #pragma unroll
            for (int mf = 0; mf < 2; mf++) {
                const int m  = wm * 32 + mf * 16 + (lane & 15);
                const int kk = ks + ((lane >> 4) << 3);
                af[mf] = *(const f16x8*)&As[m * 64 + (kk ^ ((m & 7) << 3))];
            }
            #pragma unroll
            for (int nf = 0; nf < 2; nf++) {
                const int nn = wn * 32 + nf * 16 + (lane & 15);
                const int kk = ks + ((lane >> 4) << 3);
                bf[nf] = *(const f16x8*)&Bs[nn * 64 + (kk ^ ((nn & 7) << 3))];
            }
            #pragma unroll
            for (int mf = 0; mf < 2; mf++)
                #pragma unroll
                for (int nf = 0; nf < 2; nf++)
                    acc[mf][nf] = __builtin_amdgcn_mfma_f32_16x16x32_f16(
                        af[mf], bf[nf], acc[mf][nf], 0, 0, 0);
        }
        __syncthreads();
    }

    #pragma unroll
    for (int nf = 0; nf < 2; nf++) {
        const int nc = n0 + wn * 32 + nf * 16 + (lane & 15);
        if (nc < N) {
            float* x2p = nullptr;
            if (SC) {
                const unsigned b2i = (unsigned)nc / (unsigned)Lout;
                const int l = nc - (int)b2i * Lout;
                x2p = x2d + (size_t)b2i * (C_ * 4096) + (size_t)l * stride * 65 + offset;
            }
            #pragma unroll
            for (int mf = 0; mf < 2; mf++) {
                #pragma unroll
                for (int j = 0; j < 4; j++) {
                    const int row = wm * 32 + mf * 16 + ((lane >> 4) << 2) + j;
                    const int co  = m0 + row;
                    float v = acc[mf][nf][j] + bias[co];
                    v = fmaxf(v, 0.0f);
                    yout[(size_t)co * N + nc] = (f16)v;
                    if (SC) x2p[(size_t)co * 4096] = v;
                }
            }
        }
    }
}

// MaxPool1d(k=3,s=2) + relu; optional legacy scatter
template<int SC>
__global__ void maxpool_k(const f16* __restrict__ xin, f16* __restrict__ yout,
                          float* __restrict__ x2d, int Lin, int Lp,
                          int stride, int offset)
{
    const int Nout = B_ * Lp;
    const int n = blockIdx.x * 256 + threadIdx.x;
    const int c = blockIdx.y;
    if (n >= Nout) return;
    const unsigned b = (unsigned)n / (unsigned)Lp;
    const int l = n - (int)b * Lp;
    const f16* s = xin + (size_t)c * (B_ * Lin) + (size_t)b * Lin + 2 * l;
    float v = fmaxf(fmaxf((float)s[0], (float)s[1]), (float)s[2]);
    v = fmaxf(v, 0.0f);
    yout[(size_t)c * Nout + n] = (f16)v;
    if (SC) x2d[((size_t)b * C_ + c) * 4096 + (size_t)l * stride * 65 + offset] = v;
}

// mask (always) + (i,j) -> {rel = colbase*32768 + l, Lt} lookup table (if given)
__global__ void prep_kernel(float* __restrict__ mout, int2* __restrict__ table)
{
    const int t = blockIdx.x * 256 + threadIdx.x;   // 0..4095
    const int i = t >> 6, j = t & 63;
    const int d = j - i;
    int cb = -1, l = 0, Lt = 0;
    if (d >= 0 && d <= 15) {
        cb = 64 * d - (d * (d - 1)) / 2; l = i; Lt = 64 - d;
    } else if (d >= 17 && d <= 31 && (d & 1) && ((i & 1) == 0)) {
        const int v = (d - 17) >> 1;
        cb = 904 + 24 * v - (v * (v - 1)) / 2; l = i >> 1; Lt = 24 - v;
    } else if (d >= 35 && (((d - 35) & 3) == 0) && ((i & 3) == 0)) {
        const int v = (d - 35) >> 2;
        cb = 1068 + 8 * v - (v * (v - 1)) / 2; l = i >> 2; Lt = 8 - v;
    }
    mout[t] = (cb >= 0) ? 1.0f : 0.0f;
    if (table) table[t] = make_int2(cb >= 0 ? cb * COLSLOT + l : 0, Lt);
}

// write every x2d element exactly once, coalesced; gather from compact chain
__global__ __launch_bounds__(256)
void assemble_kernel(const f16* __restrict__ chain, const int2* __restrict__ table,
                     float* __restrict__ x2d)
{
    const int c = blockIdx.x;          // 512
    const int b = blockIdx.y;          // 64
    const int tid = threadIdx.x;
    const int i  = tid >> 2;
    const int jb = (tid & 3) << 4;
    const int cb64 = c * B_ + b;
    float out[16];
    #pragma unroll
    for (int jj = 0; jj < 16; jj++) {
        const int2 e = table[(i << 6) + jb + jj];
        float v = 0.0f;
        if (e.y) v = (float)chain[(size_t)e.x + (size_t)cb64 * e.y];
        out[jj] = v;
    }
    float4* dst = (float4*)(x2d + ((((size_t)b * C_ + c) << 6 | i) << 6) + jb);
    #pragma unroll
    for (int q = 0; q < 4; q++) dst[q] = ((const float4*)out)[q];
}

extern "C" void kernel_launch(void* const* d_in, const int* in_sizes, int n_in,
                              void* d_out, int out_size, void* d_ws, size_t ws_size,
                              hipStream_t stream)
{
    const float* x  = (const float*)d_in[0];
    const float* w1 = (const float*)d_in[1];
    const float* b1 = (const float*)d_in[2];
    const float* w2 = (const float*)d_in[3];
    const float* b2 = (const float*)d_in[4];
    float* x2d   = (float*)d_out;
    float* maskp = x2d + X2D_ELEMS;

    const size_t CHAIN_BYTES = (size_t)COLS_TOTAL * COLSLOT * sizeof(f16); // 72.3 MB
    const size_t NEEDED = CHAIN_BYTES + 4096 * sizeof(int2);
    const int counts[3] = {16, 8, 8};

    if (ws_size >= NEEDED) {
        // ---- fast path: compact chain + final coalesced assemble, no memset
        f16*  chain = (f16*)d_ws;
        int2* table = (int2*)((char*)d_ws + CHAIN_BYTES);
        prep_kernel<<<16, 256, 0, stream>>>(maskp, table);

        int L = 64, k2 = 0, cb = 0;
        f16* prev = nullptr;
        for (int level = 0; level < 3; level++) {
            for (int order = 0; order < counts[level]; order++) {
                f16* outp = chain + (size_t)cb * COLSLOT;
                if (level == 0 && order == 0) {
                    conv_gemm<0, 0><<<dim3(64, 8), 256, 0, stream>>>(
                        x, w1, b1, outp, nullptr, 64, 64, 512, 0, 0);
                } else if (level > 0 && order == 0) {
                    const int Lp = (L - 3) / 2 + 1;
                    maxpool_k<0><<<dim3((B_ * Lp + 255) / 256, C_), 256, 0, stream>>>(
                        prev, outp, nullptr, L, Lp, 0, 0);
                    L = Lp;
                } else {
                    const int Lout = L - 1, N = B_ * Lout;
                    conv_gemm<1, 0><<<dim3((N + 63) / 64, 8), 256, 0, stream>>>(
                        prev, w2 + (size_t)k2 * C_ * C_ * 2, b2 + (size_t)k2 * C_,
                        outp, nullptr, L, Lout, 1024, 0, 0);
                    k2++; L = Lout;
                }
                prev = outp; cb += L;
            }
        }
        assemble_kernel<<<dim3(C_, B_), 256, 0, stream>>>(chain, table, x2d);
    } else {
        // ---- fallback: R1 memset + scatter path (needs only 8 MB ws)
        f16* buf0 = (f16*)d_ws;
        f16* buf1 = buf0 + (size_t)C_ * 4096;
        hipMemsetAsync(d_out, 0, X2D_ELEMS * sizeof(float), stream);
        prep_kernel<<<16, 256, 0, stream>>>(maskp, nullptr);

        int stride = 1, offset = 0, L = 64, k2 = 0;
        f16* cur = buf0; f16* nxt = buf1;
        for (int level = 0; level < 3; level++) {
            for (int order = 0; order < counts[level]; order++) {
                if (level == 0 && order == 0) {
                    conv_gemm<0, 1><<<dim3(64, 8), 256, 0, stream>>>(
                        x, w1, b1, buf0, x2d, 64, 64, 512, stride, offset);
                    cur = buf0; nxt = buf1;
                } else if (level > 0 && order == 0) {
                    const int Lp = (L - 3) / 2 + 1;
                    maxpool_k<1><<<dim3((B_ * Lp + 255) / 256, C_), 256, 0, stream>>>(
                        cur, nxt, x2d, L, Lp, stride, offset);
                    L = Lp; f16* t = cur; cur = nxt; nxt = t;
                } else {
                    const int Lout = L - 1, N = B_ * Lout;
                    conv_gemm<1, 1><<<dim3((N + 63) / 64, 8), 256, 0, stream>>>(
                        cur, w2 + (size_t)k2 * C_ * C_ * 2, b2 + (size_t)k2 * C_,
                        nxt, x2d, L, Lout, 1024, stride, offset);
                    k2++; L = Lout; f16* t = cur; cur = nxt; nxt = t;
                }
                offset += stride;
            }
            offset += stride; stride *= 2;
        }
    }
}

// Round 3
// 1103.903 us; speedup vs baseline: 1.8101x; 1.6362x over previous
//
#include <hip/hip_runtime.h>

typedef _Float16 f16;
typedef f16 f16x8 __attribute__((ext_vector_type(8)));
typedef f16 f16x4 __attribute__((ext_vector_type(4)));
typedef float f32x4 __attribute__((ext_vector_type(4)));

#define B_ 64
#define C_ 512
#define X2D_ELEMS ((size_t)134217728)  // 64*512*64*64
#define COLS_TOTAL 1104                // sum of L_t over all 32 layers
#define ROWLEN 1104                    // chainT row: [b][c][ROWLEN] f16

// ---------------------------------------------------------------------------
// conv-as-GEMM: Y[co][n] = relu( sum_k W[co][k] * X[k][n] + bias[co] )
//   MODE 0: first layer, k=1 conv, input fp32 [B][C][L], K=512
//   MODE 1: k=2 conv, K=1024
//   SC 0: chainT layout [b][c][1104] (fast path), col bases cb_in/cb_out
//   SC 1: legacy fallback — compact [c][b*l] bufs + fp32 scatter onto x2d
// ---------------------------------------------------------------------------
template<int MODE, int SC>
__global__ __launch_bounds__(256)
void conv_gemm(const void* __restrict__ xin_, const float* __restrict__ w,
               const float* __restrict__ bias, f16* __restrict__ yout,
               float* __restrict__ x2d, int Lin, int Lout, int K,
               int cb_in, int cb_out, int stride, int offset)
{
    const int N = B_ * Lout;
    __shared__ __align__(16) f16 As[64 * 64];
    __shared__ __align__(16) f16 Bs[64 * 64];
    const int tid  = threadIdx.x;
    const int lane = tid & 63;
    const int wv   = tid >> 6;
    const int wm   = wv >> 1, wn = wv & 1;
    const int n0 = blockIdx.x * 64, m0 = blockIdx.y * 64;

    const int bn = tid & 63;
    int n_g = n0 + bn; if (n_g > N - 1) n_g = N - 1;   // clamp tail
    const unsigned bb = (unsigned)n_g / (unsigned)Lout;
    const int bl = n_g - (int)bb * Lout;
    const int swzB = (bn & 7) << 3;

    f32x4 acc[2][2] = {};

    for (int kt = 0; kt < K; kt += 64) {
        {   // stage A: w[m0+m][kt+k] fp32 -> f16, swizzled LDS [m][k]
            const int m  = tid >> 2;
            const int k4 = (tid & 3) << 4;
            const float* src = w + (size_t)(m0 + m) * K + kt + k4;
            const int swzA = (m & 7) << 3;
            #pragma unroll
            for (int i = 0; i < 4; i++) {
                const float4 v = *(const float4*)(src + 4 * i);
                f16x4 h; h[0] = (f16)v.x; h[1] = (f16)v.y; h[2] = (f16)v.z; h[3] = (f16)v.w;
                *(f16x4*)&As[m * 64 + ((k4 + 4 * i) ^ swzA)] = h;
            }
        }
        if (MODE == 0) {   // stage B from fp32 [B][C][64]
            const float* xf = (const float*)xin_;
            #pragma unroll
            for (int it = 0; it < 16; it++) {
                const int kk = (tid >> 6) + (it << 2);
                const float v = xf[(size_t)bb * (C_ * 64) + (size_t)(kt + kk) * 64 + bl];
                Bs[bn * 64 + (kk ^ swzB)] = (f16)v;
            }
        } else {           // stage B from f16 chain, taps t=0,1
            const f16* xh = (const f16*)xin_;
            #pragma unroll
            for (int it = 0; it < 8; it++) {
                const int cis = (tid >> 6) + (it << 2);
                const int ci  = (kt >> 1) + cis;
                const f16* p;
                if (SC == 0)
                    p = xh + ((size_t)bb * C_ + ci) * ROWLEN + cb_in + bl;
                else
                    p = xh + (size_t)ci * (B_ * Lin) + (size_t)bb * Lin + bl;
                union { f16 h[2]; unsigned u; } pk;
                pk.h[0] = p[0]; pk.h[1] = p[1];
                *(unsigned*)&Bs[bn * 64 + ((cis << 1) ^ swzB)] = pk.u;
            }
        }
        __syncthreads();
        #pragma unroll
        for (int ks = 0; ks < 64; ks += 32) {
            f16x8 af[2], bf[2];
            #pragma unroll
            for (int mf = 0; mf < 2; mf++) {
                const int m  = wm * 32 + mf * 16 + (lane & 15);
                const int kk = ks + ((lane >> 4) << 3);
                af[mf] = *(const f16x8*)&As[m * 64 + (kk ^ ((m & 7) << 3))];
            }
            #pragma unroll
            for (int nf = 0; nf < 2; nf++) {
                const int nn = wn * 32 + nf * 16 + (lane & 15);
                const int kk = ks + ((lane >> 4) << 3);
                bf[nf] = *(const f16x8*)&Bs[nn * 64 + (kk ^ ((nn & 7) << 3))];
            }
            #pragma unroll
            for (int mf = 0; mf < 2; mf++)
                #pragma unroll
                for (int nf = 0; nf < 2; nf++)
                    acc[mf][nf] = __builtin_amdgcn_mfma_f32_16x16x32_f16(
                        af[mf], bf[nf], acc[mf][nf], 0, 0, 0);
        }
        __syncthreads();
    }

    #pragma unroll
    for (int nf = 0; nf < 2; nf++) {
        const int nc = n0 + wn * 32 + nf * 16 + (lane & 15);
        if (nc < N) {
            const unsigned b2i = (unsigned)nc / (unsigned)Lout;
            const int l = nc - (int)b2i * Lout;
            float* x2p = nullptr;
            if (SC) x2p = x2d + (size_t)b2i * (C_ * 4096) + (size_t)l * stride * 65 + offset;
            #pragma unroll
            for (int mf = 0; mf < 2; mf++) {
                #pragma unroll
                for (int j = 0; j < 4; j++) {
                    const int row = wm * 32 + mf * 16 + ((lane >> 4) << 2) + j;
                    const int co  = m0 + row;
                    float v = acc[mf][nf][j] + bias[co];
                    v = fmaxf(v, 0.0f);
                    if (SC == 0)
                        yout[((size_t)b2i * C_ + co) * ROWLEN + cb_out + l] = (f16)v;
                    else {
                        yout[(size_t)co * N + nc] = (f16)v;
                        x2p[(size_t)co * 4096] = v;
                    }
                }
            }
        }
    }
}

// MaxPool1d(k=3,s=2) + relu
template<int SC>
__global__ void maxpool_k(const f16* __restrict__ xin, f16* __restrict__ yout,
                          float* __restrict__ x2d, int Lin, int Lp,
                          int cb_in, int cb_out, int stride, int offset)
{
    const int Nout = B_ * Lp;
    const int n = blockIdx.x * 256 + threadIdx.x;
    const int c = blockIdx.y;
    if (n >= Nout) return;
    const unsigned b = (unsigned)n / (unsigned)Lp;
    const int l = n - (int)b * Lp;
    const f16* s;
    if (SC == 0) s = xin + ((size_t)b * C_ + c) * ROWLEN + cb_in + 2 * l;
    else         s = xin + (size_t)c * (B_ * Lin) + (size_t)b * Lin + 2 * l;
    float v = fmaxf(fmaxf((float)s[0], (float)s[1]), (float)s[2]);
    v = fmaxf(v, 0.0f);
    if (SC == 0) yout[((size_t)b * C_ + c) * ROWLEN + cb_out + l] = (f16)v;
    else {
        yout[(size_t)c * Nout + n] = (f16)v;
        x2d[((size_t)b * C_ + c) * 4096 + (size_t)l * stride * 65 + offset] = v;
    }
}

// mask[i][j]: closed-form union of all 32 written diagonals
__global__ void mask_kernel(float* __restrict__ mout)
{
    const int t = blockIdx.x * 256 + threadIdx.x;   // 0..4095
    const int i = t >> 6, j = t & 63;
    const int d = j - i;
    const bool m = (d >= 0 && d <= 15) ||
                   (d >= 17 && d <= 31 && (d & 1) && ((i & 1) == 0)) ||
                   (d >= 35 && d <= 63 && (((d - 35) & 3) == 0) && ((i & 3) == 0));
    mout[t] = m ? 1.0f : 0.0f;
}

// ---------------------------------------------------------------------------
// assemble v2: block = (b, group of 8 c). Stage 8 chainT rows (17.6 KB) into
// LDS with coalesced float4 reads; gather per-element from LDS (closed-form
// (i,j)->col); write x2d fully coalesced, every element exactly once.
// ---------------------------------------------------------------------------
__global__ __launch_bounds__(256)
void assemble2(const f16* __restrict__ chainT, float* __restrict__ x2d)
{
    __shared__ __align__(16) f16 lds[8 * ROWLEN];
    const int b  = blockIdx.x;        // 64
    const int cg = blockIdx.y;        // 64 groups of 8 c
    const int tid = threadIdx.x;

    const float4* src = (const float4*)(chainT + ((size_t)b * C_ + cg * 8) * ROWLEN);
    float4* dlds = (float4*)lds;
    #pragma unroll
    for (int t = 0; t < 5; t++) {
        const int idx = tid + t * 256;
        if (idx < 8 * ROWLEN / 8) dlds[idx] = src[idx];   // 1104 float4s
    }

    const int i  = tid >> 2;
    const int jb = (tid & 3) << 4;
    int col[16];
    #pragma unroll
    for (int jj = 0; jj < 16; jj++) {
        const int j = jb + jj;
        const int d = j - i;
        int c = -1;
        if (d >= 0 && d <= 15) {
            c = 64 * d - (d * (d - 1)) / 2 + i;
        } else if (d >= 17 && d <= 31 && (d & 1) && !(i & 1)) {
            const int v = (d - 17) >> 1;
            c = 904 + 24 * v - (v * (v - 1)) / 2 + (i >> 1);
        } else if (d >= 35 && (((d - 35) & 3) == 0) && !(i & 3)) {
            const int v = (d - 35) >> 2;
            c = 1068 + 8 * v - (v * (v - 1)) / 2 + (i >> 2);
        }
        col[jj] = c;
    }
    __syncthreads();

    for (int c = 0; c < 8; c++) {
        alignas(16) float out[16];
        #pragma unroll
        for (int jj = 0; jj < 16; jj++)
            out[jj] = (col[jj] >= 0) ? (float)lds[c * ROWLEN + col[jj]] : 0.0f;
        float4* dst = (float4*)(x2d + ((size_t)b * C_ + cg * 8 + c) * 4096 + i * 64 + jb);
        #pragma unroll
        for (int q = 0; q < 4; q++) dst[q] = ((const float4*)out)[q];
    }
}

extern "C" void kernel_launch(void* const* d_in, const int* in_sizes, int n_in,
                              void* d_out, int out_size, void* d_ws, size_t ws_size,
                              hipStream_t stream)
{
    const float* x  = (const float*)d_in[0];
    const float* w1 = (const float*)d_in[1];
    const float* b1 = (const float*)d_in[2];
    const float* w2 = (const float*)d_in[3];
    const float* b2 = (const float*)d_in[4];
    float* x2d   = (float*)d_out;
    float* maskp = x2d + X2D_ELEMS;

    const size_t CHAIN_BYTES = (size_t)B_ * C_ * ROWLEN * sizeof(f16); // 72.3 MB
    const int counts[3] = {16, 8, 8};

    mask_kernel<<<16, 256, 0, stream>>>(maskp);

    if (ws_size >= CHAIN_BYTES) {
        // ---- fast path: chainT [b][c][1104] + coalesced assemble, no memset
        f16* chain = (f16*)d_ws;
        int L = 64, k2 = 0, cb = 0, prev_cb = 0;
        for (int level = 0; level < 3; level++) {
            for (int order = 0; order < counts[level]; order++) {
                if (level == 0 && order == 0) {
                    conv_gemm<0, 0><<<dim3(64, 8), 256, 0, stream>>>(
                        x, w1, b1, chain, nullptr, 64, 64, 512, 0, cb, 0, 0);
                } else if (level > 0 && order == 0) {
                    const int Lp = (L - 3) / 2 + 1;
                    maxpool_k<0><<<dim3((B_ * Lp + 255) / 256, C_), 256, 0, stream>>>(
                        chain, chain, nullptr, L, Lp, prev_cb, cb, 0, 0);
                    L = Lp;
                } else {
                    const int Lout = L - 1, N = B_ * Lout;
                    conv_gemm<1, 0><<<dim3((N + 63) / 64, 8), 256, 0, stream>>>(
                        chain, w2 + (size_t)k2 * C_ * C_ * 2, b2 + (size_t)k2 * C_,
                        chain, nullptr, L, Lout, 1024, prev_cb, cb, 0, 0);
                    k2++; L = Lout;
                }
                prev_cb = cb; cb += L;
            }
        }
        assemble2<<<dim3(B_, 64), 256, 0, stream>>>(chain, x2d);
    } else {
        // ---- fallback: memset + scatter path (needs only 8 MB ws)
        f16* buf0 = (f16*)d_ws;
        f16* buf1 = buf0 + (size_t)C_ * 4096;
        hipMemsetAsync(d_out, 0, X2D_ELEMS * sizeof(float), stream);

        int stride = 1, offset = 0, L = 64, k2 = 0;
        f16* cur = buf0; f16* nxt = buf1;
        for (int level = 0; level < 3; level++) {
            for (int order = 0; order < counts[level]; order++) {
                if (level == 0 && order == 0) {
                    conv_gemm<0, 1><<<dim3(64, 8), 256, 0, stream>>>(
                        x, w1, b1, buf0, x2d, 64, 64, 512, 0, 0, stride, offset);
                    cur = buf0; nxt = buf1;
                } else if (level > 0 && order == 0) {
                    const int Lp = (L - 3) / 2 + 1;
                    maxpool_k<1><<<dim3((B_ * Lp + 255) / 256, C_), 256, 0, stream>>>(
                        cur, nxt, x2d, L, Lp, 0, 0, stride, offset);
                    L = Lp; f16* t = cur; cur = nxt; nxt = t;
                } else {
                    const int Lout = L - 1, N = B_ * Lout;
                    conv_gemm<1, 1><<<dim3((N + 63) / 64, 8), 256, 0, stream>>>(
                        cur, w2 + (size_t)k2 * C_ * C_ * 2, b2 + (size_t)k2 * C_,
                        nxt, x2d, L, Lout, 1024, 0, 0, stride, offset);
                    k2++; L = Lout; f16* t = cur; cur = nxt; nxt = t;
                }
                offset += stride;
            }
            offset += stride; stride *= 2;
        }
    }
}

// Round 4
// 652.012 us; speedup vs baseline: 3.0646x; 1.6931x over previous
//
#include <hip/hip_runtime.h>

typedef _Float16 f16;
typedef f16 f16x8 __attribute__((ext_vector_type(8)));
typedef f16 f16x4 __attribute__((ext_vector_type(4)));
typedef f16 f16x2 __attribute__((ext_vector_type(2)));
typedef float f32x4 __attribute__((ext_vector_type(4)));

#define B_ 64
#define C_ 512
#define X2D_ELEMS ((size_t)134217728)  // 64*512*64*64
#define CHAIN_PITCH 1104               // cols per b in chain [b][col][512]

// (i,j) -> chain column, or -1 if not on any written diagonal
__device__ __forceinline__ int col_of(int i, int j) {
    const int d = j - i;
    if (d < 0) return -1;
    if (d <= 15) return 64 * d - (d * (d - 1)) / 2 + i;
    if (d >= 17 && d <= 31 && (d & 1) && !(i & 1)) {
        const int v = (d - 17) >> 1;
        return 904 + 24 * v - (v * (v - 1)) / 2 + (i >> 1);
    }
    if (d >= 35 && !((d - 35) & 3) && !(i & 3)) {
        const int v = (d - 35) >> 2;
        return 1068 + 8 * v - (v * (v - 1)) / 2 + (i >> 2);
    }
    return -1;
}

// ---------------------------------------------------------------------------
// conv as GEMM, channel-last chain. K ordering: k = t*512 + ci.
// Block: 64 co (m) x G batches (G*Lout n-cols). 4 waves, each 16 co x 64 n.
// B staged ONCE in LDS (rows = G*Lin <= 64, 1 KB/row, chunk-XOR swizzle);
// A (f16 weights) read per-fragment from global (L2-resident);
// K-loop has no barriers.
// ---------------------------------------------------------------------------
template<int K, int TAPS>
__global__ __launch_bounds__(256, 2)
void conv_fused(const f16* __restrict__ xin, int in_pitch, int cb_in,
                const f16* __restrict__ Wl, const float* __restrict__ bias,
                f16* __restrict__ chain, int cb_out,
                int Lin, int Lout, int G)
{
    __shared__ f16 Bs[64 * 512];   // 64 KB
    const int tid = threadIdx.x, lane = tid & 63, wv = tid >> 6;
    const int b0 = blockIdx.x * G, m0 = blockIdx.y * 64;
    const int rows = G * Lin;

    // ---- stage input rows once: row r holds input[b0 + r/Lin][cb_in + r%Lin][*]
    for (int r = wv; r < rows; r += 4) {
        const int g = r / Lin, l = r - g * Lin;
        const f16* src = xin + (((size_t)(b0 + g) * in_pitch + cb_in + l) << 9);
        const f16x8 v = *(const f16x8*)(src + (lane << 3));
        *(f16x8*)&Bs[(r << 9) + ((lane ^ (r & 7)) << 3)] = v;
    }

    // ---- per-thread n mapping (n = nf*16 + lane&15 -> batch g, position l)
    int vg[4], vl[4], row0[4]; bool val[4];
    #pragma unroll
    for (int nf = 0; nf < 4; nf++) {
        const int v = nf * 16 + (lane & 15);
        vg[nf] = v / Lout; vl[nf] = v - vg[nf] * Lout;
        val[nf] = vg[nf] < G;
        row0[nf] = val[nf] ? vg[nf] * Lin + vl[nf] : 0;
    }
    const int kg = lane >> 4;
    const f16* wp = Wl + (size_t)(m0 + wv * 16 + (lane & 15)) * K + (kg << 3);

    __syncthreads();

    // ---- barrier-free K loop
    f32x4 acc[4] = {};
    #pragma unroll 4
    for (int k0 = 0; k0 < K; k0 += 32) {
        const f16x8 af = *(const f16x8*)(wp + k0);
        const int t = (TAPS == 2 && k0 >= 512) ? 1 : 0;
        const int cchunk = (((TAPS == 2) ? (k0 & 511) : k0) >> 3) + kg;
        #pragma unroll
        for (int nf = 0; nf < 4; nf++) {
            const int r = row0[nf] + t;
            const f16x8 bf = *(const f16x8*)&Bs[(r << 9) + ((cchunk ^ (r & 7)) << 3)];
            acc[nf] = __builtin_amdgcn_mfma_f32_16x16x32_f16(af, bf, acc[nf], 0, 0, 0);
        }
    }

    // ---- epilogue: bias + relu, 8 B packed stores into chain
    const int co0 = m0 + wv * 16 + ((lane >> 4) << 2);
    const float4 bb = *(const float4*)&bias[co0];
    #pragma unroll
    for (int nf = 0; nf < 4; nf++) {
        if (!val[nf]) continue;
        f16x4 h;
        #pragma unroll
        for (int j = 0; j < 4; j++)
            h[j] = (f16)fmaxf(acc[nf][j] + ((const float*)&bb)[j], 0.0f);
        *(f16x4*)&chain[(((size_t)(b0 + vg[nf]) * CHAIN_PITCH + cb_out + vl[nf]) << 9) + co0] = h;
    }
}

// MaxPool1d(k=3,s=2) + relu, channel-last: block=(l, b), threads over c-pairs
__global__ void maxpool2(f16* __restrict__ chain, int cb_in, int cb_out)
{
    const int l = blockIdx.x, b = blockIdx.y, tid = threadIdx.x;
    const f16* s = chain + (((size_t)b * CHAIN_PITCH + cb_in + 2 * l) << 9) + 2 * tid;
    f16x2 o;
    o[0] = (f16)fmaxf(fmaxf(fmaxf((float)s[0], (float)s[512]), (float)s[1024]), 0.0f);
    o[1] = (f16)fmaxf(fmaxf(fmaxf((float)s[1], (float)s[513]), (float)s[1025]), 0.0f);
    *(f16x2*)&chain[(((size_t)b * CHAIN_PITCH + cb_out + l) << 9) + 2 * tid] = o;
}

// mask: closed-form union of all 32 diagonals
__global__ void mask_kernel(float* __restrict__ mout)
{
    const int t = blockIdx.x * 256 + threadIdx.x;   // 0..4095
    const int i = t >> 6, j = t & 63;
    mout[t] = (col_of(i, j) >= 0) ? 1.0f : 0.0f;
}

// weights fp32 -> f16, reordered to [co][t*512+ci]
__global__ void wprep(const float* __restrict__ w1, const float* __restrict__ w2,
                      f16* __restrict__ Wf)
{
    size_t idx = (size_t)blockIdx.x * 256 + threadIdx.x;
    if (idx < 262144) {            // w1 [co][ci][1] -> direct
        Wf[idx] = (f16)w1[idx];
    } else {
        idx -= 262144;             // w2 [k2][co][ci][2]
        const int k2 = idx >> 18;
        const int rem = idx & 262143;
        const int co = rem >> 9, ci = rem & 511;
        const float2 v = *(const float2*)&w2[((((size_t)k2 << 9) + co) << 10) + (ci << 1)];
        f16* base = Wf + 262144 + ((size_t)k2 << 19) + ((size_t)co << 10);
        base[ci] = (f16)v.x;
        base[512 + ci] = (f16)v.y;
    }
}

// x fp32 [b][512][64] -> xT f16 [b][64 l][512 c]; block = (ci-slab of 16, b)
__global__ __launch_bounds__(256)
void xtrans(const float* __restrict__ x, f16* __restrict__ xT)
{
    __shared__ f16 t[64][20];
    const int s = blockIdx.x, b = blockIdx.y, tid = threadIdx.x;
    const int ci = tid >> 4, l0 = (tid & 15) << 2;
    const float4 v = *(const float4*)&x[(((size_t)b * C_ + s * 16 + ci) << 6) + l0];
    t[l0 + 0][ci] = (f16)v.x; t[l0 + 1][ci] = (f16)v.y;
    t[l0 + 2][ci] = (f16)v.z; t[l0 + 3][ci] = (f16)v.w;
    __syncthreads();
    const int l = tid >> 2, q = tid & 3;
    const f16x4 o = *(const f16x4*)&t[l][q << 2];
    *(f16x4*)&xT[((((size_t)b << 6) + l) << 9) + (s << 4) + (q << 2)] = o;
}

// ---------------------------------------------------------------------------
// assemble v3: block=(i, b). Stage valid chain cols for row i by j into LDS
// (zero rows for invalid j), coalesced; then fully-coalesced float4 x2d write,
// transposing via swizzled scalar LDS reads (hidden under the write stream).
// ---------------------------------------------------------------------------
__global__ __launch_bounds__(256)
void assemble3(const f16* __restrict__ chain, float* __restrict__ x2d)
{
    __shared__ f16 J[64 * 512];    // 64 KB, row j, chunk-XOR swizzled
    const int tid = threadIdx.x, lane = tid & 63, wv = tid >> 6;
    const int i = blockIdx.x, b = blockIdx.y;

    for (int j = wv; j < 64; j += 4) {
        const int col = col_of(i, j);
        f16x8 v = {0, 0, 0, 0, 0, 0, 0, 0};
        if (col >= 0)
            v = *(const f16x8*)(chain + (((size_t)b * CHAIN_PITCH + col) << 9) + (lane << 3));
        *(f16x8*)&J[(j << 9) + ((lane ^ (j & 7)) << 3)] = v;
    }
    __syncthreads();

    const int jq = tid & 15, c0 = tid >> 4;
    float* dst0 = x2d + (((size_t)b * C_) << 12) + (i << 6) + (jq << 2);
    for (int ct = 0; ct < 32; ct++) {
        const int c = c0 + (ct << 4);
        const int cj = c >> 3;
        float4 o;
        #pragma unroll
        for (int jj = 0; jj < 4; jj++) {
            const int j = (jq << 2) + jj;
            ((float*)&o)[jj] = (float)J[(j << 9) + ((cj ^ (j & 7)) << 3) + (c & 7)];
        }
        *(float4*)(dst0 + ((size_t)c << 12)) = o;
    }
}

extern "C" void kernel_launch(void* const* d_in, const int* in_sizes, int n_in,
                              void* d_out, int out_size, void* d_ws, size_t ws_size,
                              hipStream_t stream)
{
    const float* x  = (const float*)d_in[0];
    const float* w1 = (const float*)d_in[1];
    const float* b1 = (const float*)d_in[2];
    const float* w2 = (const float*)d_in[3];
    const float* b2 = (const float*)d_in[4];
    float* x2d   = (float*)d_out;
    float* maskp = x2d + X2D_ELEMS;

    // chain in d_ws (72.3 MB, proven available); f16 weights + xT live in the
    // d_out x2d region (35 MB scratch) — fully overwritten by assemble3 later.
    f16* chain = (f16*)d_ws;
    f16* Wf = (f16*)x2d;
    f16* xT = Wf + 262144 + (size_t)29 * 524288;

    mask_kernel<<<16, 256, 0, stream>>>(maskp);
    wprep<<<(30 * 262144) / 256, 256, 0, stream>>>(w1, w2, Wf);
    xtrans<<<dim3(32, B_), 256, 0, stream>>>(x, xT);

    const int counts[3] = {16, 8, 8};
    int L = 64, k2 = 0, cb = 0, prev = 0;
    for (int level = 0; level < 3; level++) {
        for (int order = 0; order < counts[level]; order++) {
            if (level == 0 && order == 0) {
                conv_fused<512, 1><<<dim3(64, 8), 256, 0, stream>>>(
                    xT, 64, 0, Wf, b1, chain, cb, 64, 64, 1);
            } else if (level > 0 && order == 0) {
                const int Lp = (L - 3) / 2 + 1;
                maxpool2<<<dim3(Lp, B_), 256, 0, stream>>>(chain, prev, cb);
                L = Lp;
            } else {
                const int Lout = L - 1;
                int G = 1;
                while ((G * 2) * Lout <= 64 && (G * 2) * L <= 64) G *= 2;
                conv_fused<1024, 2><<<dim3(64 / G, 8), 256, 0, stream>>>(
                    chain, CHAIN_PITCH, prev,
                    Wf + 262144 + (size_t)k2 * 524288, b2 + (size_t)k2 * C_,
                    chain, cb, L, Lout, G);
                k2++; L = Lout;
            }
            prev = cb; cb += L;
        }
    }
    assemble3<<<dim3(64, B_), 256, 0, stream>>>(chain, x2d);
}